// Round 3
// baseline (452.909 us; speedup 1.0000x reference)
//
#include <hip/hip_runtime.h>
#include <math.h>

// LinearAttention B=16 L=8192 D=256 H=4 dh=32
//   gemm1 (split-bf16 MFMA, counted-vmcnt pipeline): qkv = x@W_qkv
//     colblk 0 -> q hi/lo bf16 [BL,128]
//     colblk 1 -> k fp32 into kvhb[bh][l][0..31]
//     colblk 2 -> v fp32 into kvhb[bh][l][32..63]
//     XCD-grouped grid: 3 col-blocks of one row-block share an XCD's L2
//   ksum (register-blocked 4dx8e per thread, 2048 blocks): S=sum_l e^k v, Z=sum e^k
//   combine: M2T[b][n][c] = scale * (S/Z) @ W_out   (split hi/lo bf16)
//   gemm2 (split-bf16 MFMA, counted-vmcnt pipeline): out[b] = q[b]@M2[b] + b_out
// T4 schedule: raw s_barrier + s_waitcnt vmcnt(8) (never 0 in main loop), so the
// next tile's 8 global_load_lds stay in flight across compute+barrier+frag-read.

#define BL 131072

typedef __attribute__((ext_vector_type(8))) short bf16x8;
typedef __attribute__((ext_vector_type(4))) float f32x4;
typedef __attribute__((ext_vector_type(4))) unsigned u32x4;

__device__ __forceinline__ unsigned cvt_pk2(float a, float b) {
    unsigned r;
    asm("v_cvt_pk_bf16_f32 %0, %1, %2" : "=v"(r) : "v"(a), "v"(b));
    return r;
}
__device__ __forceinline__ ushort bf16_rn(float f) {
    return (ushort)cvt_pk2(f, f);
}
__device__ __forceinline__ float bf16f(ushort h) { return __uint_as_float(((unsigned)h) << 16); }

__device__ __forceinline__ void glds16(const void* g, void* l) {
    __builtin_amdgcn_global_load_lds((const __attribute__((address_space(1))) unsigned int*)g,
                                     (__attribute__((address_space(3))) unsigned int*)l,
                                     16, 0, 0);
}

// merged: W_qkv [256,384] -> WT hi/lo bf16 [384,256]  +  zero S/Z
__global__ __launch_bounds__(256) void prep_kernel(const float* __restrict__ W,
                                                   ushort* __restrict__ wh,
                                                   ushort* __restrict__ wl,
                                                   float* __restrict__ S,
                                                   float* __restrict__ Z) {
    int n = blockIdx.x, k = threadIdx.x;
    float f = W[k * 384 + n];
    ushort h = bf16_rn(f);
    wh[n * 256 + k] = h;
    wl[n * 256 + k] = bf16_rn(f - bf16f(h));
    int i = n * 256 + k;
    if (i < 65536) S[i] = 0.f;
    if (i < 2048) Z[i] = 0.f;
}

// gemm1: [131072x256] @ [256x384], A fp32 (split in-kernel), B=WT hi/lo bf16.
// grid 3072 (1D): xcd = wg&7, slot = wg>>3, cb = slot%3, yb = (slot/3)*8+xcd.
__global__ __launch_bounds__(256) void gemm1_kernel(
    const float* __restrict__ X,
    const ushort* __restrict__ Wh, const ushort* __restrict__ Wl,
    ushort* __restrict__ Qh, ushort* __restrict__ Ql,
    float* __restrict__ KV) {
    __shared__ __align__(16) float  As[2][4096];   // 128r x 32k fp32, chunk p = q ^ (r&7)
    __shared__ __align__(16) ushort Bsh[2][4096];  // 128r x 32k bf16, chunk p = q ^ ((r>>1)&3)
    __shared__ __align__(16) ushort Bsl[2][4096];
    const int tid = threadIdx.x;
    const int wg = blockIdx.x;
    const int xcd = wg & 7;
    const int slot = wg >> 3;
    const int cb = slot % 3;
    const int yb = (slot / 3) * 8 + xcd;
    const int col0 = cb * 128;
    const int row0 = yb * 128;
    const int lane = tid & 63, wave = tid >> 6;
    const int wr = (wave & 1) * 64, wc = (wave >> 1) * 64;
    const int m = lane & 15, quad = lane >> 4;
    const int ra = lane >> 3, pa = lane & 7;   // A staging: 8 rows/seg, 8 chunks(16B)/row
    const int rb = lane >> 2, pb = lane & 3;   // B staging: 16 rows/seg, 4 chunks/row

    f32x4 acc[4][4] = {};

    auto STAGE = [&](int buf, int k0) {        // 8 glds16 per thread
#pragma unroll
        for (int s = 0; s < 4; ++s) {          // A: 16 segs of 1KB
            int seg = s * 4 + wave;
            int r = seg * 8 + ra;
            int q = pa ^ (r & 7);
            glds16(&X[(long)(row0 + r) * 256 + k0 + q * 4], &As[buf][seg * 256]);
        }
#pragma unroll
        for (int s = 0; s < 2; ++s) {          // Bh/Bl: 8 segs each
            int seg = s * 4 + wave;
            int r = seg * 16 + rb;
            int q = pb ^ ((r >> 1) & 3);
            glds16(&Wh[(long)(col0 + r) * 256 + k0 + q * 8], &Bsh[buf][seg * 512]);
            glds16(&Wl[(long)(col0 + r) * 256 + k0 + q * 8], &Bsl[buf][seg * 512]);
        }
    };

    STAGE(0, 0);
    STAGE(1, 32);

    for (int kt = 0; kt < 8; ++kt) {
        const int cur = kt & 1;
        if (kt < 7) asm volatile("s_waitcnt vmcnt(8)" ::: "memory");  // cur landed; next stays in flight
        else        asm volatile("s_waitcnt vmcnt(0)" ::: "memory");
        __builtin_amdgcn_s_barrier();
        __builtin_amdgcn_sched_barrier(0);

        // A frags first (longest dep chain: read -> convert -> MFMA)
        f32x4 a0v[4], a1v[4];
#pragma unroll
        for (int i = 0; i < 4; ++i) {
            int r = wr + i * 16 + m;
            int p0 = (quad * 2) ^ (r & 7);
            int p1 = (quad * 2 + 1) ^ (r & 7);
            a0v[i] = *(const f32x4*)&As[cur][r * 32 + p0 * 4];
            a1v[i] = *(const f32x4*)&As[cur][r * 32 + p1 * 4];
        }
        bf16x8 bh[4], bl[4];
#pragma unroll
        for (int i = 0; i < 4; ++i) {
            int r = wc + i * 16 + m;
            int p = quad ^ ((r >> 1) & 3);
            bh[i] = *(const bf16x8*)&Bsh[cur][r * 32 + p * 8];
            bl[i] = *(const bf16x8*)&Bsl[cur][r * 32 + p * 8];
        }
#pragma unroll
        for (int i = 0; i < 4; ++i) {
            u32x4 ahw, alw;
#pragma unroll
            for (int e = 0; e < 2; ++e) {
                float f0 = a0v[i][2 * e], f1 = a0v[i][2 * e + 1];
                unsigned h = cvt_pk2(f0, f1);
                ahw[e] = h;
                alw[e] = cvt_pk2(f0 - __uint_as_float(h << 16),
                                 f1 - __uint_as_float(h & 0xFFFF0000u));
            }
#pragma unroll
            for (int e = 0; e < 2; ++e) {
                float f0 = a1v[i][2 * e], f1 = a1v[i][2 * e + 1];
                unsigned h = cvt_pk2(f0, f1);
                ahw[2 + e] = h;
                alw[2 + e] = cvt_pk2(f0 - __uint_as_float(h << 16),
                                     f1 - __uint_as_float(h & 0xFFFF0000u));
            }
            bf16x8 ah = __builtin_bit_cast(bf16x8, ahw);
            bf16x8 al = __builtin_bit_cast(bf16x8, alw);
            __builtin_amdgcn_s_setprio(1);
#pragma unroll
            for (int j = 0; j < 4; ++j) {
                acc[i][j] = __builtin_amdgcn_mfma_f32_16x16x32_bf16(ah, bh[j], acc[i][j], 0, 0, 0);
                acc[i][j] = __builtin_amdgcn_mfma_f32_16x16x32_bf16(ah, bl[j], acc[i][j], 0, 0, 0);
                acc[i][j] = __builtin_amdgcn_mfma_f32_16x16x32_bf16(al, bh[j], acc[i][j], 0, 0, 0);
            }
            __builtin_amdgcn_s_setprio(0);
        }
        __builtin_amdgcn_sched_barrier(0);
        __builtin_amdgcn_s_barrier();      // all waves done reading cur
        __builtin_amdgcn_sched_barrier(0);
        if (kt < 6) STAGE(cur, (kt + 2) * 32);
    }

    if (cb == 0) {                   // q -> hi/lo bf16 [BL,128]
#pragma unroll
        for (int i = 0; i < 4; ++i)
#pragma unroll
            for (int r4 = 0; r4 < 4; ++r4) {
                long row = row0 + wr + i * 16 + quad * 4 + r4;
#pragma unroll
                for (int j = 0; j < 4; ++j) {
                    float v = acc[i][j][r4];
                    int col = wc + j * 16 + m;
                    ushort h = bf16_rn(v);
                    Qh[row * 128 + col] = h;
                    Ql[row * 128 + col] = bf16_rn(v - bf16f(h));
                }
            }
    } else {                         // k (cb=1) / v (cb=2) -> kvhb[bh][l][64]
        int vofs = (cb == 2) ? 32 : 0;
#pragma unroll
        for (int i = 0; i < 4; ++i)
#pragma unroll
            for (int r4 = 0; r4 < 4; ++r4) {
                long row = row0 + wr + i * 16 + quad * 4 + r4;
                long b = row >> 13, l = row & 8191;
#pragma unroll
                for (int j = 0; j < 4; ++j) {
                    int c = wc + j * 16 + m;
                    int h = c >> 5, dd = c & 31;
                    KV[(((b * 4 + h) * 8192 + l) * 64) + vofs + dd] = acc[i][j][r4];
                }
            }
    }
}

// S[d,e] = sum_l e^{k[l,d]} v[l,e]; Z_d = sum_l e^{k}. grid = bh*32+chunk (2048 blocks).
// Register-blocked: thread owns 4d x 8e outputs, 1/8 of the l's; 3 ds_read_b128/l.
// LDS layout: idx(l,c) = l*64 + (l>>3)*4 + c  (16B aligned, lg spreads banks).
__global__ __launch_bounds__(256) void ksum_hb(const float* __restrict__ KV,
                                               float* __restrict__ S,
                                               float* __restrict__ Z) {
    int bx = blockIdx.x;
    int chunk = bx & 31, bh = bx >> 5;
    const float* slab = KV + ((long)bh * 8192 + chunk * 256) * 64;
    __shared__ float tile[4128];
    const int tid = threadIdx.x;
    const int w = tid >> 6, lane = tid & 63;
    const int lg = lane >> 3, cc = lane & 7;
    const int combo = w * 8 + cc;        // 0..31 -> (dq, eo)
    const int d0 = (combo >> 2) * 4;
    const int e0 = (combo & 3) * 8;
    const int c4 = tid & 15, lrow = tid >> 4;   // loader: float4 id
    float z4[4] = {0.f, 0.f, 0.f, 0.f};
    float acc[4][8] = {};

    for (int t0 = 0; t0 < 256; t0 += 64) {
#pragma unroll
        for (int u = 0; u < 4; ++u) {
            int l = u * 16 + lrow;
            float4 wv = *(const float4*)&slab[((long)(t0 + l)) * 64 + c4 * 4];
            if (c4 < 8) { wv.x = __expf(wv.x); wv.y = __expf(wv.y); wv.z = __expf(wv.z); wv.w = __expf(wv.w); }
            *(float4*)&tile[l * 64 + (l >> 3) * 4 + c4 * 4] = wv;
        }
        __syncthreads();
#pragma unroll
        for (int j = 0; j < 8; ++j) {
            int l = lg * 8 + j;
            int base = l * 64 + lg * 4;
            f32x4 ev = *(const f32x4*)&tile[base + d0];
            f32x4 v0 = *(const f32x4*)&tile[base + 32 + e0];
            f32x4 v1 = *(const f32x4*)&tile[base + 36 + e0];
#pragma unroll
            for (int q = 0; q < 4; ++q) {
                float e = ev[q];
                z4[q] += e;
                acc[q][0] += e * v0[0]; acc[q][1] += e * v0[1];
                acc[q][2] += e * v0[2]; acc[q][3] += e * v0[3];
                acc[q][4] += e * v1[0]; acc[q][5] += e * v1[1];
                acc[q][6] += e * v1[2]; acc[q][7] += e * v1[3];
            }
        }
        __syncthreads();
    }
    // reduce over lg (lane bits 3..5)
#pragma unroll
    for (int q = 0; q < 4; ++q) {
        z4[q] += __shfl_xor(z4[q], 8);
        z4[q] += __shfl_xor(z4[q], 16);
        z4[q] += __shfl_xor(z4[q], 32);
#pragma unroll
        for (int j = 0; j < 8; ++j) {
            acc[q][j] += __shfl_xor(acc[q][j], 8);
            acc[q][j] += __shfl_xor(acc[q][j], 16);
            acc[q][j] += __shfl_xor(acc[q][j], 32);
        }
    }
    if (lg == 0) {
#pragma unroll
        for (int q = 0; q < 4; ++q)
#pragma unroll
            for (int j = 0; j < 8; ++j)
                atomicAdd(&S[((long)bh * 32 + d0 + q) * 32 + e0 + j], acc[q][j]);
        if ((cc & 3) == 0)
#pragma unroll
            for (int q = 0; q < 4; ++q)
                atomicAdd(&Z[bh * 32 + d0 + q], z4[q]);
    }
}

// M2T[b][n][h*32+d] = scale * (S[d,e]/Z_d) @ W_out[h*32+e, n], split hi/lo. grid B*H.
__global__ __launch_bounds__(256) void combine_kernel(const float* __restrict__ S,
                                                      const float* __restrict__ Z,
                                                      const float* __restrict__ Wout,
                                                      ushort* __restrict__ m2h,
                                                      ushort* __restrict__ m2l) {
    int bh = blockIdx.x;
    int b = bh >> 2, h = bh & 3;
    int n = threadIdx.x;
    __shared__ float ctx[32][32];
    __shared__ float zs[32];
    if (n < 32) zs[n] = Z[bh * 32 + n];
    __syncthreads();
#pragma unroll
    for (int t = 0; t < 4; ++t) {
        int idx = t * 256 + n;
        int d = idx >> 5, e = idx & 31;
        ctx[d][e] = S[(long)bh * 1024 + idx] / zs[d];
    }
    __syncthreads();
    const float scale = 0.17677669529663687f; // 1/sqrt(32)
    float acc[32];
#pragma unroll
    for (int d = 0; d < 32; ++d) acc[d] = 0.f;
    for (int e = 0; e < 32; ++e) {
        float w = Wout[(h * 32 + e) * 256 + n];
#pragma unroll
        for (int d = 0; d < 32; ++d) acc[d] += ctx[d][e] * w;
    }
#pragma unroll
    for (int d = 0; d < 32; ++d) {
        float v = acc[d] * scale;
        long idx = ((long)(b * 256 + n)) * 128 + h * 32 + d;
        ushort hh = bf16_rn(v);
        m2h[idx] = hh;
        m2l[idx] = bf16_rn(v - bf16f(hh));
    }
}

// gemm2: per-b [8192x128] @ [128x256] + bias. A=q hi/lo, B=M2T hi/lo (both [N][K] bf16).
// grid 2048 (1D): xcd = bid&7, u = bid>>3, cb = u&1, id = (u>>1)*8+xcd -> (bz, yb).
__global__ __launch_bounds__(256) void gemm2_kernel(
    const ushort* __restrict__ Ahp, const ushort* __restrict__ Alp,
    const ushort* __restrict__ Bhp, const ushort* __restrict__ Blp,
    const float* __restrict__ bias, float* __restrict__ out) {
    __shared__ __align__(16) ushort Ash[2][4096];
    __shared__ __align__(16) ushort Asl[2][4096];
    __shared__ __align__(16) ushort Bsh[2][4096];
    __shared__ __align__(16) ushort Bsl[2][4096];
    const int tid = threadIdx.x;
    const int bid = blockIdx.x;
    const int xcd = bid & 7;
    const int u = bid >> 3;
    const int cbl = u & 1;
    const int id = (u >> 1) * 8 + xcd;       // 0..1023
    const int col0 = cbl * 128;
    const int row0 = (id & 63) * 128;
    const long bz = id >> 6;
    const ushort* Ah = Ahp + bz * (8192L * 128);
    const ushort* Al = Alp + bz * (8192L * 128);
    const ushort* Bh = Bhp + bz * (256L * 128);
    const ushort* Bl = Blp + bz * (256L * 128);
    const int lane = tid & 63, wave = tid >> 6;
    const int wr = (wave & 1) * 64, wc = (wave >> 1) * 64;
    const int m = lane & 15, quad = lane >> 4;
    const int rb = lane >> 2, pb = lane & 3;

    f32x4 acc[4][4] = {};

    auto STAGE = [&](int buf, int k0) {       // 8 glds16 per thread
#pragma unroll
        for (int s = 0; s < 2; ++s) {
            int seg = s * 4 + wave;
            int r = seg * 16 + rb;
            int q = pb ^ ((r >> 1) & 3);
            glds16(&Ah[(long)(row0 + r) * 128 + k0 + q * 8], &Ash[buf][seg * 512]);
            glds16(&Al[(long)(row0 + r) * 128 + k0 + q * 8], &Asl[buf][seg * 512]);
            glds16(&Bh[(long)(col0 + r) * 128 + k0 + q * 8], &Bsh[buf][seg * 512]);
            glds16(&Bl[(long)(col0 + r) * 128 + k0 + q * 8], &Bsl[buf][seg * 512]);
        }
    };

    STAGE(0, 0);
    STAGE(1, 32);

    for (int kt = 0; kt < 4; ++kt) {
        const int cur = kt & 1;
        if (kt < 3) asm volatile("s_waitcnt vmcnt(8)" ::: "memory");
        else        asm volatile("s_waitcnt vmcnt(0)" ::: "memory");
        __builtin_amdgcn_s_barrier();
        __builtin_amdgcn_sched_barrier(0);

        bf16x8 af[2][4], bg[2][4];
#pragma unroll
        for (int i = 0; i < 4; ++i) {
            int rA = wr + i * 16 + m;
            int pA = quad ^ ((rA >> 1) & 3);
            af[0][i] = *(const bf16x8*)&Ash[cur][rA * 32 + pA * 8];
            af[1][i] = *(const bf16x8*)&Asl[cur][rA * 32 + pA * 8];
            int rB = wc + i * 16 + m;
            int pB = quad ^ ((rB >> 1) & 3);
            bg[0][i] = *(const bf16x8*)&Bsh[cur][rB * 32 + pB * 8];
            bg[1][i] = *(const bf16x8*)&Bsl[cur][rB * 32 + pB * 8];
        }
        __builtin_amdgcn_s_setprio(1);
#pragma unroll
        for (int i = 0; i < 4; ++i)
#pragma unroll
            for (int j = 0; j < 4; ++j) {
                acc[i][j] = __builtin_amdgcn_mfma_f32_16x16x32_bf16(af[0][i], bg[0][j], acc[i][j], 0, 0, 0);
                acc[i][j] = __builtin_amdgcn_mfma_f32_16x16x32_bf16(af[0][i], bg[1][j], acc[i][j], 0, 0, 0);
                acc[i][j] = __builtin_amdgcn_mfma_f32_16x16x32_bf16(af[1][i], bg[0][j], acc[i][j], 0, 0, 0);
            }
        __builtin_amdgcn_s_setprio(0);
        __builtin_amdgcn_sched_barrier(0);
        __builtin_amdgcn_s_barrier();
        __builtin_amdgcn_sched_barrier(0);
        if (kt < 2) STAGE(cur, (kt + 2) * 32);
    }

    float bv[4];
#pragma unroll
    for (int j = 0; j < 4; ++j) bv[j] = bias[col0 + wc + j * 16 + m];
    float* outb = out + bz * (8192L * 256);
#pragma unroll
    for (int i = 0; i < 4; ++i)
#pragma unroll
        for (int r4 = 0; r4 < 4; ++r4) {
            long row = row0 + wr + i * 16 + quad * 4 + r4;
#pragma unroll
            for (int j = 0; j < 4; ++j)
                outb[row * 256 + col0 + wc + j * 16 + m] = acc[i][j][r4] + bv[j];
        }
}

extern "C" void kernel_launch(void* const* d_in, const int* in_sizes, int n_in,
                              void* d_out, int out_size, void* d_ws, size_t ws_size,
                              hipStream_t stream) {
    const float* x     = (const float*)d_in[0];
    const float* W_qkv = (const float*)d_in[1];
    const float* W_out = (const float*)d_in[2];
    const float* b_out = (const float*)d_in[3];
    float* out = (float*)d_out;

    char* p = (char*)d_ws;
    float* kv   = (float*)p;  p += (long)64 * 8192 * 64 * 4;   // head-blocked [bh][l][k32|v32]
    float* S    = (float*)p;  p += 65536 * 4;
    float* Z    = (float*)p;  p += 2048 * 4;
    ushort* wth = (ushort*)p; p += 384 * 256 * 2;
    ushort* wtl = (ushort*)p; p += 384 * 256 * 2;
    ushort* qh  = (ushort*)p; p += (long)BL * 128 * 2;
    ushort* ql  = (ushort*)p; p += (long)BL * 128 * 2;
    ushort* m2h = (ushort*)p; p += 16 * 256 * 128 * 2;
    ushort* m2l = (ushort*)p; p += 16 * 256 * 128 * 2;

    prep_kernel<<<384, 256, 0, stream>>>(W_qkv, wth, wtl, S, Z);

    gemm1_kernel<<<3072, 256, 0, stream>>>(x, wth, wtl, qh, ql, kv);

    ksum_hb<<<2048, 256, 0, stream>>>(kv, S, Z);
    combine_kernel<<<64, 256, 0, stream>>>(S, Z, W_out, m2h, m2l);

    gemm2_kernel<<<2048, 256, 0, stream>>>(qh, ql, m2h, m2l, b_out, out);
}

// Round 4
// 382.102 us; speedup vs baseline: 1.1853x; 1.1853x over previous
//
#include <hip/hip_runtime.h>
#include <math.h>

// LinearAttention B=16 L=8192 D=256 H=4 dh=32 — fused-dataflow version
//   prep:    W_qkv cols 128..383 -> WT hi/lo bf16 [256 col][256 k]
//   gemm_kv: per 64-row block: [64x256]@[256x256] (split-bf16 MFMA) -> k,v in acc
//            -> exp(k),v to LDS fp32 tile -> VALU outer-product -> S_part, Z_part
//            (no KV materialization, no atomics)
//   combine: S = sum(S_part), Z = sum(Z_part); ctx = S/Z; M2 = scale*ctx@W_out (fp32)
//   w2eff:   W2[b] = Wq @ M2[b]  ->  hi/lo bf16 [b][n][k]   (q folded away:
//            out = (x@Wq)@M2 = x@(Wq@M2))
//   gemm2:   out[b] = x[b] @ W2[b] + b_out   (A = x fp32 split in-kernel, K=256)
// Split precision: a=hi+lo; keep Ah*Bh+Ah*Bl+Al*Bh (drop ~2^-18 Al*Bl term).
// Staging: global_load_lds width=16, XOR-swizzled source so frag ds_read_b128
// are <=2-way bank aliased (free).

typedef __attribute__((ext_vector_type(8))) short bf16x8;
typedef __attribute__((ext_vector_type(4))) float f32x4;
typedef __attribute__((ext_vector_type(4))) unsigned u32x4;

__device__ __forceinline__ unsigned cvt_pk2(float a, float b) {
    unsigned r;
    asm("v_cvt_pk_bf16_f32 %0, %1, %2" : "=v"(r) : "v"(a), "v"(b));
    return r;
}
__device__ __forceinline__ ushort bf16_rn(float f) {
    return (ushort)cvt_pk2(f, f);
}
__device__ __forceinline__ float bf16f(ushort h) { return __uint_as_float(((unsigned)h) << 16); }

__device__ __forceinline__ void glds16(const void* g, void* l) {
    __builtin_amdgcn_global_load_lds((const __attribute__((address_space(1))) unsigned int*)g,
                                     (__attribute__((address_space(3))) unsigned int*)l,
                                     16, 0, 0);
}

// W_qkv [256,384] cols 128..383 -> WT hi/lo bf16 [256 col][256 k]
__global__ __launch_bounds__(256) void prep_kernel(const float* __restrict__ W,
                                                   ushort* __restrict__ wh,
                                                   ushort* __restrict__ wl) {
    int n = blockIdx.x, k = threadIdx.x;          // n: local col (qkv col 128+n)
    float f = W[k * 384 + 128 + n];
    ushort h = bf16_rn(f);
    wh[n * 256 + k] = h;
    wl[n * 256 + k] = bf16_rn(f - bf16f(h));
}

// gemm_kv: grid 2048 (64-row tiles), 256 thr = 4 waves; wave w owns cols w*64..+63.
// k-loop: A = X fp32 (split in-kernel), B = WT hi/lo. Epilogue: ek/v tile + S outer.
__global__ __launch_bounds__(256) void gemm_kv(
    const float* __restrict__ X,
    const ushort* __restrict__ Wh, const ushort* __restrict__ Wl,
    float* __restrict__ S_part, float* __restrict__ Z_part) {
    __shared__ __align__(16) char smem[66560];
    float*  As  = (float*)smem;                 // [8 seg][256 f] = 8 KB, chunk p = q^(r&7)
    ushort* Bsh = (ushort*)(smem + 8192);       // [16 seg][512] = 16 KB, p = q^((r>>1)&3)
    ushort* Bsl = (ushort*)(smem + 8192 + 16384);
    float*  tile = (float*)smem;                // after k-loop: [64][260] fp32 ek|v

    const int tid = threadIdx.x;
    const int blk = blockIdx.x;
    const long row0 = (long)blk * 64;
    const int lane = tid & 63, wave = tid >> 6;
    const int wc = wave * 64;
    const int m = lane & 15, quad = lane >> 4;
    const int ra = lane >> 3, pa = lane & 7;
    const int rb = lane >> 2, pb = lane & 3;

    f32x4 acc[4][4] = {};

    for (int k0 = 0; k0 < 256; k0 += 32) {
#pragma unroll
        for (int s = 0; s < 2; ++s) {          // A: 8 segs of 1KB
            int seg = s * 4 + wave;
            int r = seg * 8 + ra;
            int q = pa ^ (r & 7);
            glds16(&X[(row0 + r) * 256 + k0 + q * 4], &As[seg * 256]);
        }
#pragma unroll
        for (int s = 0; s < 4; ++s) {          // Bh/Bl: 16 segs each
            int seg = s * 4 + wave;
            int r = seg * 16 + rb;
            int q = pb ^ ((r >> 1) & 3);
            glds16(&Wh[r * 256 + k0 + q * 8], &Bsh[seg * 512]);
            glds16(&Wl[r * 256 + k0 + q * 8], &Bsl[seg * 512]);
        }
        __syncthreads();

        bf16x8 bh[4], bl[4];
#pragma unroll
        for (int j = 0; j < 4; ++j) {
            int r = wc + j * 16 + m;
            int p = quad ^ ((r >> 1) & 3);
            bh[j] = *(const bf16x8*)&Bsh[r * 32 + p * 8];
            bl[j] = *(const bf16x8*)&Bsl[r * 32 + p * 8];
        }
#pragma unroll
        for (int i = 0; i < 4; ++i) {
            int r = i * 16 + m;
            int p0 = (quad * 2) ^ (r & 7);
            int p1 = (quad * 2 + 1) ^ (r & 7);
            f32x4 a0 = *(const f32x4*)&As[r * 32 + p0 * 4];
            f32x4 a1 = *(const f32x4*)&As[r * 32 + p1 * 4];
            u32x4 ahw, alw;
#pragma unroll
            for (int e = 0; e < 2; ++e) {
                float f0 = a0[2 * e], f1 = a0[2 * e + 1];
                unsigned h = cvt_pk2(f0, f1);
                ahw[e] = h;
                alw[e] = cvt_pk2(f0 - __uint_as_float(h << 16),
                                 f1 - __uint_as_float(h & 0xFFFF0000u));
            }
#pragma unroll
            for (int e = 0; e < 2; ++e) {
                float f0 = a1[2 * e], f1 = a1[2 * e + 1];
                unsigned h = cvt_pk2(f0, f1);
                ahw[2 + e] = h;
                alw[2 + e] = cvt_pk2(f0 - __uint_as_float(h << 16),
                                     f1 - __uint_as_float(h & 0xFFFF0000u));
            }
            bf16x8 ah = __builtin_bit_cast(bf16x8, ahw);
            bf16x8 al = __builtin_bit_cast(bf16x8, alw);
#pragma unroll
            for (int j = 0; j < 4; ++j) {
                acc[i][j] = __builtin_amdgcn_mfma_f32_16x16x32_bf16(ah, bh[j], acc[i][j], 0, 0, 0);
                acc[i][j] = __builtin_amdgcn_mfma_f32_16x16x32_bf16(ah, bl[j], acc[i][j], 0, 0, 0);
                acc[i][j] = __builtin_amdgcn_mfma_f32_16x16x32_bf16(al, bh[j], acc[i][j], 0, 0, 0);
            }
        }
        __syncthreads();
    }

    // epilogue 1: write exp(k)|v fp32 tile [64][260] (cols 0..127 = e^k, 128..255 = v)
#pragma unroll
    for (int i = 0; i < 4; ++i)
#pragma unroll
        for (int r4 = 0; r4 < 4; ++r4) {
            int rl = i * 16 + quad * 4 + r4;
#pragma unroll
            for (int j = 0; j < 4; ++j) {
                int c = wc + j * 16 + m;
                float v = acc[i][j][r4];
                tile[rl * 260 + c] = (c < 128) ? __expf(v) : v;
            }
        }
    __syncthreads();

    // epilogue 2: S[d,e] partials. thread -> h = wave, d = lane>>1, e-half = lane&1.
    const int h = wave, d = lane >> 1, eg = lane & 1, e0 = eg * 16;
    float sacc[16] = {};
    float z = 0.f;
#pragma unroll 4
    for (int l = 0; l < 64; ++l) {
        const float* rowp = &tile[l * 260];
        float ek = rowp[h * 32 + d];
        const f32x4* vp = (const f32x4*)&rowp[128 + h * 32 + e0];
        f32x4 v0 = vp[0], v1 = vp[1], v2 = vp[2], v3 = vp[3];
        z += ek;
        sacc[0]  += ek * v0[0]; sacc[1]  += ek * v0[1]; sacc[2]  += ek * v0[2]; sacc[3]  += ek * v0[3];
        sacc[4]  += ek * v1[0]; sacc[5]  += ek * v1[1]; sacc[6]  += ek * v1[2]; sacc[7]  += ek * v1[3];
        sacc[8]  += ek * v2[0]; sacc[9]  += ek * v2[1]; sacc[10] += ek * v2[2]; sacc[11] += ek * v2[3];
        sacc[12] += ek * v3[0]; sacc[13] += ek * v3[1]; sacc[14] += ek * v3[2]; sacc[15] += ek * v3[3];
    }
    long sb = (long)blk * 4096 + h * 1024 + d * 32 + e0;
#pragma unroll
    for (int t = 0; t < 16; ++t) S_part[sb + t] = sacc[t];
    if (eg == 0) Z_part[blk * 128 + h * 32 + d] = z;
}

// combine: per bh, reduce 128 partials; ctx = S/Z; M2[b][hd][n] = scale*ctx@W_out. grid 64.
__global__ __launch_bounds__(256) void combine_kernel(const float* __restrict__ S_part,
                                                      const float* __restrict__ Z_part,
                                                      const float* __restrict__ Wout,
                                                      float* __restrict__ m2f) {
    int bh = blockIdx.x;
    int b = bh >> 2, h = bh & 3;
    int n = threadIdx.x;
    __shared__ float ctx[32][33];
    __shared__ float zs[32];
    if (n < 32) {
        float z = 0.f;
        for (int j = 0; j < 128; ++j) z += Z_part[(b * 128 + j) * 128 + h * 32 + n];
        zs[n] = z;
    }
    float s4[4] = {};
    for (int j = 0; j < 128; ++j) {
        const float* sp = &S_part[((long)(b * 128 + j)) * 4096 + h * 1024];
#pragma unroll
        for (int t = 0; t < 4; ++t) s4[t] += sp[t * 256 + n];
    }
    __syncthreads();
#pragma unroll
    for (int t = 0; t < 4; ++t) {
        int idx = t * 256 + n;
        ctx[idx >> 5][idx & 31] = s4[t] / zs[idx >> 5];
    }
    __syncthreads();
    const float scale = 0.17677669529663687f; // 1/sqrt(32)
    float acc[32];
#pragma unroll
    for (int dd = 0; dd < 32; ++dd) acc[dd] = 0.f;
    for (int e = 0; e < 32; ++e) {
        float w = Wout[(h * 32 + e) * 256 + n];
#pragma unroll
        for (int dd = 0; dd < 32; ++dd) acc[dd] += ctx[dd][e] * w;
    }
#pragma unroll
    for (int dd = 0; dd < 32; ++dd)
        m2f[((long)(b * 128 + h * 32 + dd)) * 256 + n] = acc[dd] * scale;
}

// w2eff: W2[b][k][n] = sum_hd Wq[k][hd]*M2[b][hd][n]; store hi/lo bf16 [b][n][k].
// grid (16 b x 16 kg).
__global__ __launch_bounds__(256) void w2eff_kernel(const float* __restrict__ Wqkv,
                                                    const float* __restrict__ m2f,
                                                    ushort* __restrict__ w2h,
                                                    ushort* __restrict__ w2l) {
    int bid = blockIdx.x;
    int b = bid >> 4, kg = bid & 15;
    int n = threadIdx.x;
    __shared__ float lWq[16 * 128];
#pragma unroll
    for (int u = 0; u < 8; ++u) {
        int idx = u * 256 + n;
        int k = idx >> 7, hd = idx & 127;
        lWq[idx] = Wqkv[(kg * 16 + k) * 384 + hd];   // Wq = cols 0..127
    }
    __syncthreads();
    float acc[16] = {};
    for (int hd = 0; hd < 128; ++hd) {
        float mm = m2f[((long)(b * 128 + hd)) * 256 + n];
#pragma unroll
        for (int k = 0; k < 16; ++k) acc[k] += lWq[k * 128 + hd] * mm;
    }
    long base = ((long)(b * 256 + n)) * 256 + kg * 16;
#pragma unroll
    for (int k = 0; k < 16; ++k) {
        ushort hh = bf16_rn(acc[k]);
        w2h[base + k] = hh;
        w2l[base + k] = bf16_rn(acc[k] - bf16f(hh));
    }
}

// gemm2: out[b] = x[b][8192x256] @ W2[b][256x256] + bias. A fp32 split in-kernel,
// B hi/lo bf16 [n][k]. grid 2048: xcd = wg&7, u = wg>>3, cb = u&1, gid = (u>>1)*8+xcd.
__global__ __launch_bounds__(256) void gemm2_kernel(
    const float* __restrict__ X,
    const ushort* __restrict__ W2h, const ushort* __restrict__ W2l,
    const float* __restrict__ bias, float* __restrict__ out) {
    __shared__ __align__(16) float  As[4096];   // 128r x 32k fp32
    __shared__ __align__(16) ushort Bsh[4096];  // 128r x 32k bf16
    __shared__ __align__(16) ushort Bsl[4096];
    const int tid = threadIdx.x;
    const int wg = blockIdx.x;
    const int xcd = wg & 7;
    const int u = wg >> 3;
    const int cbl = u & 1;
    const int gid = (u >> 1) * 8 + xcd;        // 0..1023
    const long bz = gid >> 6;
    const int row0 = (gid & 63) * 128;
    const int col0 = cbl * 128;
    const float* Xb = X + bz * (8192L * 256);
    const ushort* Bh = W2h + bz * (256L * 256);
    const ushort* Bl = W2l + bz * (256L * 256);
    const int lane = tid & 63, wave = tid >> 6;
    const int wr = (wave & 1) * 64, wc = (wave >> 1) * 64;
    const int m = lane & 15, quad = lane >> 4;
    const int ra = lane >> 3, pa = lane & 7;
    const int rb = lane >> 2, pb = lane & 3;

    f32x4 acc[4][4] = {};

    for (int k0 = 0; k0 < 256; k0 += 32) {
#pragma unroll
        for (int s = 0; s < 4; ++s) {          // A: 16 segs
            int seg = s * 4 + wave;
            int r = seg * 8 + ra;
            int q = pa ^ (r & 7);
            glds16(&Xb[(long)(row0 + r) * 256 + k0 + q * 4], &As[seg * 256]);
        }
#pragma unroll
        for (int s = 0; s < 2; ++s) {          // Bh/Bl: 8 segs each
            int seg = s * 4 + wave;
            int r = seg * 16 + rb;
            int q = pb ^ ((r >> 1) & 3);
            glds16(&Bh[(col0 + r) * 256 + k0 + q * 8], &Bsh[seg * 512]);
            glds16(&Bl[(col0 + r) * 256 + k0 + q * 8], &Bsl[seg * 512]);
        }
        __syncthreads();

        bf16x8 bh[4], bl[4];
#pragma unroll
        for (int j = 0; j < 4; ++j) {
            int r = wc + j * 16 + m;
            int p = quad ^ ((r >> 1) & 3);
            bh[j] = *(const bf16x8*)&Bsh[r * 32 + p * 8];
            bl[j] = *(const bf16x8*)&Bsl[r * 32 + p * 8];
        }
#pragma unroll
        for (int i = 0; i < 4; ++i) {
            int r = wr + i * 16 + m;
            int p0 = (quad * 2) ^ (r & 7);
            int p1 = (quad * 2 + 1) ^ (r & 7);
            f32x4 a0 = *(const f32x4*)&As[r * 32 + p0 * 4];
            f32x4 a1 = *(const f32x4*)&As[r * 32 + p1 * 4];
            u32x4 ahw, alw;
#pragma unroll
            for (int e = 0; e < 2; ++e) {
                float f0 = a0[2 * e], f1 = a0[2 * e + 1];
                unsigned h = cvt_pk2(f0, f1);
                ahw[e] = h;
                alw[e] = cvt_pk2(f0 - __uint_as_float(h << 16),
                                 f1 - __uint_as_float(h & 0xFFFF0000u));
            }
#pragma unroll
            for (int e = 0; e < 2; ++e) {
                float f0 = a1[2 * e], f1 = a1[2 * e + 1];
                unsigned h = cvt_pk2(f0, f1);
                ahw[2 + e] = h;
                alw[2 + e] = cvt_pk2(f0 - __uint_as_float(h << 16),
                                     f1 - __uint_as_float(h & 0xFFFF0000u));
            }
            bf16x8 ah = __builtin_bit_cast(bf16x8, ahw);
            bf16x8 al = __builtin_bit_cast(bf16x8, alw);
#pragma unroll
            for (int j = 0; j < 4; ++j) {
                acc[i][j] = __builtin_amdgcn_mfma_f32_16x16x32_bf16(ah, bh[j], acc[i][j], 0, 0, 0);
                acc[i][j] = __builtin_amdgcn_mfma_f32_16x16x32_bf16(ah, bl[j], acc[i][j], 0, 0, 0);
                acc[i][j] = __builtin_amdgcn_mfma_f32_16x16x32_bf16(al, bh[j], acc[i][j], 0, 0, 0);
            }
        }
        __syncthreads();
    }

    float bv[4];
#pragma unroll
    for (int j = 0; j < 4; ++j) bv[j] = bias[col0 + wc + j * 16 + m];
    float* outb = out + bz * (8192L * 256);
#pragma unroll
    for (int i = 0; i < 4; ++i)
#pragma unroll
        for (int r4 = 0; r4 < 4; ++r4) {
            long row = row0 + wr + i * 16 + quad * 4 + r4;
#pragma unroll
            for (int j = 0; j < 4; ++j)
                outb[row * 256 + col0 + wc + j * 16 + m] = acc[i][j][r4] + bv[j];
        }
}

extern "C" void kernel_launch(void* const* d_in, const int* in_sizes, int n_in,
                              void* d_out, int out_size, void* d_ws, size_t ws_size,
                              hipStream_t stream) {
    const float* x     = (const float*)d_in[0];
    const float* W_qkv = (const float*)d_in[1];
    const float* W_out = (const float*)d_in[2];
    const float* b_out = (const float*)d_in[3];
    float* out = (float*)d_out;

    char* p = (char*)d_ws;
    ushort* wth = (ushort*)p; p += 256 * 256 * 2;            // 128 KB
    ushort* wtl = (ushort*)p; p += 256 * 256 * 2;
    float* Sp   = (float*)p;  p += (long)2048 * 4096 * 4;    // 32 MB
    float* Zp   = (float*)p;  p += 2048 * 128 * 4;           // 1 MB
    float* m2f  = (float*)p;  p += 16 * 128 * 256 * 4;       // 2 MB
    ushort* w2h = (ushort*)p; p += (long)16 * 256 * 256 * 2; // 2 MB
    ushort* w2l = (ushort*)p; p += (long)16 * 256 * 256 * 2;

    prep_kernel<<<256, 256, 0, stream>>>(W_qkv, wth, wtl);
    gemm_kv<<<2048, 256, 0, stream>>>(x, wth, wtl, Sp, Zp);
    combine_kernel<<<64, 256, 0, stream>>>(Sp, Zp, W_out, m2f);
    w2eff_kernel<<<256, 256, 0, stream>>>(W_qkv, m2f, w2h, w2l);
    gemm2_kernel<<<2048, 256, 0, stream>>>(x, w2h, w2l, b_out, out);
}